// Round 12
// baseline (9414.322 us; speedup 1.0000x reference)
//
#include <hip/hip_runtime.h>
#include <cstdint>
#include <utility>

// Verified bit-exact (rounds 5-11, absmax 0.0): partitionable threefry split
// (block(key,0,i)), randint(0,2)=lower_bits&1, uniform=(bits>>9)|0x3f800000 - 1,
// dot = strict k-ascending fma chain from 0, sigmoid = 1/(1+exp(-x)) with
// cephes exp separate mul/add on the fx==0 path. DO NOT change any arithmetic.
//
// Perf model (r11 post-mortem): VALU and SALU both near-saturated at ~70%
// issue efficiency. This round: float4 LDS (half the ds_read issues),
// 2x1-cyc SALU selects (bitcmp+cselect, no s_mul), x=0.125 VALU-select split
// (row 0 E only) to balance VALU ~3.9k cyc vs SALU ~4.0k cyc-equiv per wave-step.

constexpr int LATENT = 128;
constexpr int NS = 524288;
constexpr int STEPS = 30;
constexpr int R = 4;                       // rows per wave
constexpr int TPB = 1024;                  // 16 waves/block; 2 blocks/CU -> 32 waves/CU
constexpr int WAVES_PB = TPB / 64;
constexpr int NWAVES = NS / R;             // 131072
constexpr int NBLOCKS = NWAVES / WAVES_PB; // 8192

typedef float f32x4 __attribute__((ext_vector_type(4)));

// ---------------- compile-time unroll helper (constexpr index for asm "n") ----
template <typename F, int... I>
__device__ __forceinline__ void unroll_impl(F&& f, std::integer_sequence<int, I...>) {
  (f(std::integral_constant<int, I>{}), ...);
}
template <int N, typename F>
__device__ __forceinline__ void unroll_n(F&& f) {
  unroll_impl(static_cast<F&&>(f), std::make_integer_sequence<int, N>{});
}

// ---------------- threefry2x32, 20 rounds, exactly jax's schedule ----------------
struct TFOut { uint32_t a, b; };

__host__ __device__ constexpr TFOut tf2x32_ct(uint32_t k0, uint32_t k1,
                                              uint32_t x0, uint32_t x1) {
  const uint32_t ks2 = k0 ^ k1 ^ 0x1BD11BDAu;
  x0 += k0; x1 += k1;
#define TFR(r) { x0 += x1; x1 = (x1 << (r)) | (x1 >> (32 - (r))); x1 ^= x0; }
  TFR(13) TFR(15) TFR(26) TFR(6)
  x0 += k1;  x1 += ks2 + 1u;
  TFR(17) TFR(29) TFR(16) TFR(24)
  x0 += ks2; x1 += k0 + 2u;
  TFR(13) TFR(15) TFR(26) TFR(6)
  x0 += k0;  x1 += k1 + 3u;
  TFR(17) TFR(29) TFR(16) TFR(24)
  x0 += k1;  x1 += ks2 + 4u;
  TFR(13) TFR(15) TFR(26) TFR(6)
  x0 += ks2; x1 += k0 + 5u;
#undef TFR
  return {x0, x1};
}

// Device version with guaranteed 1-op rotates (v_alignbit_b32).
__device__ __forceinline__ uint32_t rotl_hw(uint32_t x, int r) {
  return __builtin_amdgcn_alignbit(x, x, (uint32_t)(32 - r));
}
__device__ __forceinline__ TFOut tf2x32_dev(uint32_t k0, uint32_t k1,
                                            uint32_t x0, uint32_t x1) {
  const uint32_t ks2 = k0 ^ k1 ^ 0x1BD11BDAu;
  x0 += k0; x1 += k1;
#define TFRD(r) { x0 += x1; x1 = rotl_hw(x1, r); x1 ^= x0; }
  TFRD(13) TFRD(15) TFRD(26) TFRD(6)
  x0 += k1;  x1 += ks2 + 1u;
  TFRD(17) TFRD(29) TFRD(16) TFRD(24)
  x0 += ks2; x1 += k0 + 2u;
  TFRD(13) TFRD(15) TFRD(26) TFRD(6)
  x0 += k0;  x1 += k1 + 3u;
  TFRD(17) TFRD(29) TFRD(16) TFRD(24)
  x0 += k1;  x1 += ks2 + 4u;
  TFRD(13) TFRD(15) TFRD(26) TFRD(6)
  x0 += ks2; x1 += k0 + 5u;
#undef TFRD
  return {x0, x1};
}

// All keys derive from seed 42 -> compile-time constants.
struct Keys { uint32_t sk[62]; };
constexpr Keys make_keys() {
  Keys K{};
  const TFOut ki = tf2x32_ct(0u, 42u, 0u, 0u);        // k_init = split(key)[0]
  const TFOut kl = tf2x32_ct(0u, 42u, 0u, 1u);        // k_loop = split(key)[1]
  const TFOut k2 = tf2x32_ct(ki.a, ki.b, 0u, 1u);     // split(k_init)[1]
  K.sk[60] = k2.a; K.sk[61] = k2.b;
  for (uint32_t t = 0; t < (uint32_t)STEPS; ++t) {
    const TFOut s = tf2x32_ct(kl.a, kl.b, 0u, t);     // step_keys[t]
    K.sk[2 * t] = s.a; K.sk[2 * t + 1] = s.b;
  }
  return K;
}
__constant__ Keys KC = make_keys();

// partitionable random_bits element: bits[c] = o0^o1 of block(key, hi=0, lo=c)
__device__ __forceinline__ uint32_t rbits(uint32_t ka, uint32_t kb, uint32_t c) {
  const TFOut r = tf2x32_dev(ka, kb, 0u, c);
  return r.a ^ r.b;
}

// jax uniform f32: bitcast((bits>>9)|0x3f800000) - 1.0 (exact)
__device__ __forceinline__ float bits_to_u(uint32_t b) {
  return __fsub_rn(__uint_as_float((b >> 9) | 0x3f800000u), 1.0f);
}

// XLA:CPU sigmoid, cephes exp fx==0 path, separate mul/add (verified exact).
__device__ __forceinline__ float ref_sigmoid(float v) {
  float a = -v;
  float y = __fadd_rn(__fmul_rn(a, 1.9875691500E-4f), 1.3981999507E-3f);
  y = __fadd_rn(__fmul_rn(y, a), 8.3334519073E-3f);
  y = __fadd_rn(__fmul_rn(y, a), 4.1665795894E-2f);
  y = __fadd_rn(__fmul_rn(y, a), 1.6666665459E-1f);
  y = __fadd_rn(__fmul_rn(y, a), 5.0000001201E-1f);
  float a2 = __fmul_rn(a, a);
  y = __fadd_rn(__fmul_rn(y, a2), a);
  float e = __fadd_rn(1.0f, y);                 // exp(-v)
  return __fdiv_rn(1.0f, __fadd_rn(1.0f, e));   // 1/(1+exp(-v))
}

// Wave-uniform ballot halves into SGPRs.
__device__ __forceinline__ void ballot_scalar(int pred, uint32_t& lo, uint32_t& hi) {
  const unsigned long long b = __ballot(pred);
  lo = __builtin_amdgcn_readfirstlane((uint32_t)b);
  hi = __builtin_amdgcn_readfirstlane((uint32_t)(b >> 32));
}

// SALU select: bit B of mask -> 0x3f800000 or 0 in an SGPR. 2x 1-cyc SALU ops.
template <int B>
__device__ __forceinline__ float sel_bit_salu(uint32_t mask) {
  uint32_t f;
  asm("s_bitcmp1_b32 %1, %2\n\t"
      "s_cselect_b32 %0, 0x3f800000, 0"
      : "=s"(f) : "s"(mask), "n"(B) : "scc");
  return __uint_as_float(f);
}

// VALU select: bit B of mask -> 1.0f/0.0f in a VGPR (2 VALU ops).
template <int B>
__device__ __forceinline__ float sel_bit_valu(uint32_t mask) {
  uint32_t b; float f;
  asm("v_bfe_u32 %0, %1, %2, 1" : "=v"(b) : "s"(mask), "n"(B));
  asm("v_cvt_f32_u32 %0, %1" : "=v"(f) : "v"(b));
  return f;
}

// acc += f * w : scalar v_fmac_f32 (full-rate), f from SGPR or VGPR.
__device__ __forceinline__ void fmac_s(float& acc, float f, float w) {
  asm("v_fmac_f32 %0, %1, %2" : "+v"(acc) : "s"(f), "v"(w));
}
__device__ __forceinline__ void fmac_v(float& acc, float f, float w) {
  asm("v_fmac_f32 %0, %1, %2" : "+v"(acc) : "v"(f), "v"(w));
}

__global__ __launch_bounds__(TPB, 8)
void rbm_gibbs_kernel(const float* __restrict__ h, const float* __restrict__ W,
                      float* __restrict__ out) {
  // Ws4[m*64+l] = {W[2m][2l], W[2m][2l+1], W[2m+1][2l], W[2m+1][2l+1]}
  // -> one ds_read_b128 per (m, lane) serves both k-rows of both columns.
  __shared__ f32x4 Ws4[64 * 64];   // 64 KiB

  const int tid = threadIdx.x;
  {
    const float2* Wg2 = reinterpret_cast<const float2*>(W);
    #pragma unroll
    for (int it = 0; it < 4096 / TPB; ++it) {
      const int idx = it * TPB + tid;
      const int m = idx >> 6, l = idx & 63;
      const float2 g0 = Wg2[(2 * m) * 64 + l];
      const float2 g1 = Wg2[(2 * m + 1) * 64 + l];
      Ws4[idx] = f32x4{g0.x, g0.y, g1.x, g1.y};
    }
  }
  __syncthreads();

  const int lane = tid & 63;
  const int wid  = blockIdx.x * WAVES_PB + (tid >> 6);        // [0, NWAVES)
  const uint32_t cb = (uint32_t)wid * (uint32_t)(R * LATENT); // < 2^26
  const int j0 = 2 * lane;
  const float h0 = h[j0], h1 = h[j0 + 1];

  // ---- z0: randint lower bits & 1 ; bit l of E/O mask = z[row q][col 2l / 2l+1]
  uint32_t mElo[R], mEhi[R], mOlo[R], mOhi[R];
  {
    const uint32_t ka = KC.sk[60], kb = KC.sk[61];
    #pragma unroll
    for (int q = 0; q < R; ++q) {
      const uint32_t c = cb + (uint32_t)(q * LATENT) + (uint32_t)j0;
      ballot_scalar((int)(rbits(ka, kb, c) & 1u),      mElo[q], mEhi[q]);
      ballot_scalar((int)(rbits(ka, kb, c + 1u) & 1u), mOlo[q], mOhi[q]);
    }
  }

  #pragma unroll 1
  for (int t = 0; t < STEPS; ++t) {
    // ---- dot: strict k-ascending chain from 0; k=2m via E-bit m, k=2m+1 via O-bit m.
    // Row 0's E-selects on VALU (x=0.125), everything else on SALU.
    float ax[R], ay[R];
    #pragma unroll
    for (int q = 0; q < R; ++q) { ax[q] = 0.f; ay[q] = 0.f; }

    unroll_n<64>([&](auto MC) {
      constexpr int m = MC.value;
      constexpr int b = m & 31;
      const f32x4 w = Ws4[m * 64 + lane];
      {
        const float fE = sel_bit_valu<b>(m < 32 ? mElo[0] : mEhi[0]);
        const float fO = sel_bit_salu<b>(m < 32 ? mOlo[0] : mOhi[0]);
        fmac_v(ax[0], fE, w.x); fmac_v(ay[0], fE, w.y);
        fmac_s(ax[0], fO, w.z); fmac_s(ay[0], fO, w.w);
      }
      #pragma unroll
      for (int q = 1; q < R; ++q) {
        const float fE = sel_bit_salu<b>(m < 32 ? mElo[q] : mEhi[q]);
        const float fO = sel_bit_salu<b>(m < 32 ? mOlo[q] : mOhi[q]);
        fmac_s(ax[q], fE, w.x); fmac_s(ay[q], fE, w.y);
        fmac_s(ax[q], fO, w.z); fmac_s(ay[q], fO, w.w);
      }
    });

    // ---- uniforms + Bernoulli update
    const uint32_t sa = KC.sk[2 * t], sb = KC.sk[2 * t + 1];
    #pragma unroll
    for (int q = 0; q < R; ++q) {
      const uint32_t c = cb + (uint32_t)(q * LATENT) + (uint32_t)j0;
      const uint32_t uE = rbits(sa, sb, c);
      const uint32_t uO = rbits(sa, sb, c + 1u);
      const float pE = ref_sigmoid(__fadd_rn(h0, ax[q]));
      const float pO = ref_sigmoid(__fadd_rn(h1, ay[q]));
      ballot_scalar((int)(bits_to_u(uE) < pE), mElo[q], mEhi[q]);
      ballot_scalar((int)(bits_to_u(uO) < pO), mOlo[q], mOhi[q]);
    }
  }

  // ---- write z_final: R consecutive rows per wave, float2 per lane (coalesced)
  float2* out2 = reinterpret_cast<float2*>(out);
  #pragma unroll
  for (int q = 0; q < R; ++q) {
    float2 z;
    z.x = (float)(((lane < 32 ? mElo[q] : mEhi[q]) >> (lane & 31)) & 1u);
    z.y = (float)(((lane < 32 ? mOlo[q] : mOhi[q]) >> (lane & 31)) & 1u);
    out2[(size_t)(wid * R + q) * 64 + lane] = z;
  }
}

extern "C" void kernel_launch(void* const* d_in, const int* in_sizes, int n_in,
                              void* d_out, int out_size, void* d_ws, size_t ws_size,
                              hipStream_t stream) {
  const float* h = (const float*)d_in[0];
  const float* W = (const float*)d_in[1];
  float* out = (float*)d_out;
  rbm_gibbs_kernel<<<NBLOCKS, TPB, 0, stream>>>(h, W, out);
}